// Round 6
// baseline (466.624 us; speedup 1.0000x reference)
//
#include <hip/hip_runtime.h>
#include <cstdint>

typedef __attribute__((ext_vector_type(4))) float f32x4;
typedef __attribute__((ext_vector_type(8))) short s16x8;

__device__ inline unsigned short f2bf(float f) {
    unsigned u = __float_as_uint(f);
    unsigned r = (u + 0x7FFFu + ((u >> 16) & 1u)) >> 16;
    return (unsigned short)r;
}
__device__ inline float b2f(unsigned short h) {
    return __uint_as_float(((unsigned)h) << 16);
}

__device__ inline void gload16(const unsigned short* g, unsigned short* l) {
    __builtin_amdgcn_global_load_lds(
        (const __attribute__((address_space(1))) unsigned int*)g,
        (__attribute__((address_space(3))) unsigned int*)l, 16, 0, 0);
}

// ---------------- utility ----------------
__global__ void zero_f_kernel(float* __restrict__ p, long long n) {
    long long i = (long long)blockIdx.x * 256 + threadIdx.x;
    if (i < n) p[i] = 0.f;
}

__global__ void detect_mask_kernel(const unsigned char* __restrict__ m, int nbytes, int* __restrict__ flag) {
    __shared__ int isByte, isFloat;
    if (threadIdx.x == 0) { isByte = 0; isFloat = 0; }
    __syncthreads();
    const unsigned* w = (const unsigned*)m;
    for (int i = threadIdx.x; i < nbytes / 4; i += blockDim.x) {
        unsigned v = w[i];
        if (v == 0u || v == 1u) continue;
        if (v == 0x3f800000u) isFloat = 1; else isByte = 1;
    }
    __syncthreads();
    if (threadIdx.x == 0) *flag = isFloat ? 2 : (isByte ? 1 : 0);
}

// ---------------- CSR build ----------------
__global__ void deg_cnt_kernel(const int* __restrict__ dst, const float* __restrict__ ew,
                               float* __restrict__ degw, int* __restrict__ cnt, int E) {
    int e = blockIdx.x * 256 + threadIdx.x;
    if (e >= E) return;
    int d = dst[e];
    unsafeAtomicAdd(&degw[d], ew[e]);
    atomicAdd(&cnt[d], 1);
}

// block 0: exclusive scan of cnt -> rowstart; blocks 1..: norm = rsqrt(degw+1)
__global__ __launch_bounds__(1024) void norm_scan_kernel(const int* __restrict__ cnt,
                                                         int* __restrict__ rowstart,
                                                         float* __restrict__ degw, int P) {
    int t = threadIdx.x;
    if (blockIdx.x > 0) {
        int i = (blockIdx.x - 1) * 1024 + t;
        if (i < P) degw[i] = rsqrtf(degw[i] + 1.0f);
        return;
    }
    __shared__ int wsum[16];
    __shared__ int carry;
    int lane = t & 63, w = t >> 6;
    if (t == 0) { carry = 0; rowstart[0] = 0; }
    __syncthreads();
    for (int base = 0; base < P; base += 1024) {
        int v = (base + t < P) ? cnt[base + t] : 0;
        int x = v;
#pragma unroll
        for (int off = 1; off < 64; off <<= 1) {
            int y = __shfl_up(x, off);
            if (lane >= off) x += y;
        }
        if (lane == 63) wsum[w] = x;
        __syncthreads();
        if (w == 0) {
            int xs = (lane < 16) ? wsum[lane] : 0;
#pragma unroll
            for (int off = 1; off < 16; off <<= 1) {
                int y = __shfl_up(xs, off);
                if (lane >= off) xs += y;
            }
            if (lane < 16) wsum[lane] = xs;
        }
        __syncthreads();
        int wbase = (w == 0) ? 0 : wsum[w - 1];
        int inc = carry + wbase + x;
        if (base + t < P) rowstart[base + t + 1] = inc;
        __syncthreads();
        if (t == 1023) carry = inc;
        __syncthreads();
    }
}

__global__ void fill_kernel(const int* __restrict__ src, const int* __restrict__ dst,
                            const float* __restrict__ ew, const float* __restrict__ norm,
                            const int* __restrict__ rowstart, int* __restrict__ fill,
                            int* __restrict__ csrc, float* __restrict__ coef, int E) {
    int e = blockIdx.x * 256 + threadIdx.x;
    if (e >= E) return;
    int d = dst[e], sI = src[e];
    int pos = rowstart[d] + atomicAdd(&fill[d], 1);
    csrc[pos] = sI;
    coef[pos] = ew[e] * norm[sI] * norm[d];
}

// ---------------- x fp32 -> bf16 padded (both graphs via blockIdx.y) ----------------
__global__ void xcvt_kernel(const float* __restrict__ x0, const float* __restrict__ x1,
                            unsigned short* __restrict__ out, int P, int IN, int Kp) {
    const float* x = blockIdx.y ? x1 : x0;
    unsigned short* o0 = out + (size_t)blockIdx.y * P * Kp;
    int nch = Kp / 8;
    int idx = blockIdx.x * 256 + threadIdx.x;
    if (idx >= P * nch) return;
    int row = idx / nch, c8 = (idx - row * nch) * 8;
    const float* xr = x + (size_t)row * IN + c8;
    float v[8];
    if (c8 + 8 <= IN) {
        float2 a = *(const float2*)xr;
        float2 b = *(const float2*)(xr + 2);
        float2 c = *(const float2*)(xr + 4);
        float2 d = *(const float2*)(xr + 6);
        v[0]=a.x; v[1]=a.y; v[2]=b.x; v[3]=b.y; v[4]=c.x; v[5]=c.y; v[6]=d.x; v[7]=d.y;
    } else {
#pragma unroll
        for (int j = 0; j < 8; ++j) v[j] = (c8 + j < IN) ? xr[j] : 0.f;
    }
    ushort4 lo, hi;
    lo.x=f2bf(v[0]); lo.y=f2bf(v[1]); lo.z=f2bf(v[2]); lo.w=f2bf(v[3]);
    hi.x=f2bf(v[4]); hi.y=f2bf(v[5]); hi.z=f2bf(v[6]); hi.w=f2bf(v[7]);
    unsigned short* o = o0 + (size_t)row * Kp + c8;
    *(ushort4*)o = lo;
    *(ushort4*)(o + 4) = hi;
}

// ---------------- conv1 aggregation: writes K-concatenated [P][512] ----------------
__global__ __launch_bounds__(256) void conv1_agg_kernel(
    const unsigned short* __restrict__ Hb, const float* __restrict__ norm,
    const int* __restrict__ rowstart, const int* __restrict__ csrc, const float* __restrict__ coef,
    const float* __restrict__ b0, const float* __restrict__ b1,
    unsigned short* __restrict__ out, int P) {
    int node = blockIdx.x * 4 + (threadIdx.x >> 6);
    if (node >= P) return;
    int z = blockIdx.y;
    const unsigned short* H = Hb + (size_t)z * P * 256;
    const float* bias = z ? b1 : b0;
    int lane = threadIdx.x & 63;
    int f4 = lane * 4;
    float nn = norm[node];
    ushort4 hv = *(const ushort4*)(H + (size_t)node * 256 + f4);
    float a0 = b2f(hv.x) * nn * nn, a1 = b2f(hv.y) * nn * nn;
    float a2 = b2f(hv.z) * nn * nn, a3 = b2f(hv.w) * nn * nn;
    int s0 = rowstart[node], s1 = rowstart[node + 1];
    int p = s0;
    for (; p + 4 <= s1; p += 4) {
        int i0 = csrc[p], i1 = csrc[p + 1], i2 = csrc[p + 2], i3 = csrc[p + 3];
        float c0 = coef[p], c1 = coef[p + 1], c2 = coef[p + 2], c3 = coef[p + 3];
        ushort4 v0 = *(const ushort4*)(H + (size_t)i0 * 256 + f4);
        ushort4 v1 = *(const ushort4*)(H + (size_t)i1 * 256 + f4);
        ushort4 v2 = *(const ushort4*)(H + (size_t)i2 * 256 + f4);
        ushort4 v3 = *(const ushort4*)(H + (size_t)i3 * 256 + f4);
        a0 += b2f(v0.x) * c0 + b2f(v1.x) * c1 + b2f(v2.x) * c2 + b2f(v3.x) * c3;
        a1 += b2f(v0.y) * c0 + b2f(v1.y) * c1 + b2f(v2.y) * c2 + b2f(v3.y) * c3;
        a2 += b2f(v0.z) * c0 + b2f(v1.z) * c1 + b2f(v2.z) * c2 + b2f(v3.z) * c3;
        a3 += b2f(v0.w) * c0 + b2f(v1.w) * c1 + b2f(v2.w) * c2 + b2f(v3.w) * c3;
    }
    for (; p < s1; ++p) {
        int i0 = csrc[p];
        float c0 = coef[p];
        ushort4 v0 = *(const ushort4*)(H + (size_t)i0 * 256 + f4);
        a0 += b2f(v0.x) * c0; a1 += b2f(v0.y) * c0; a2 += b2f(v0.z) * c0; a3 += b2f(v0.w) * c0;
    }
    float4 bv = *(const float4*)(bias + f4);
    ushort4 o;
    o.x = f2bf(fmaxf(a0 + bv.x, 0.f));
    o.y = f2bf(fmaxf(a1 + bv.y, 0.f));
    o.z = f2bf(fmaxf(a2 + bv.z, 0.f));
    o.w = f2bf(fmaxf(a3 + bv.w, 0.f));
    *(ushort4*)(out + (size_t)node * 512 + z * 256 + f4) = o;
}

// ---------------- conv2 aggregation on SUMMED table T[P][64] ----------------
__global__ __launch_bounds__(256) void conv2_agg_kernel(
    const unsigned short* __restrict__ T, const float* __restrict__ norm,
    const int* __restrict__ rowstart, const int* __restrict__ csrc, const float* __restrict__ coef,
    const float* __restrict__ b0, const float* __restrict__ b1,
    float* __restrict__ s, int P) {
    int node = blockIdx.x * 4 + (threadIdx.x >> 6);
    if (node >= P) return;
    int lane = threadIdx.x & 63;
    float nn = norm[node];
    float acc = b2f(T[(size_t)node * 64 + lane]) * nn * nn;
    int s0 = rowstart[node], s1 = rowstart[node + 1];
    int p = s0;
    for (; p + 4 <= s1; p += 4) {
        int i0 = csrc[p], i1 = csrc[p + 1], i2 = csrc[p + 2], i3 = csrc[p + 3];
        float c0 = coef[p], c1 = coef[p + 1], c2 = coef[p + 2], c3 = coef[p + 3];
        acc += b2f(T[(size_t)i0 * 64 + lane]) * c0 + b2f(T[(size_t)i1 * 64 + lane]) * c1 +
               b2f(T[(size_t)i2 * 64 + lane]) * c2 + b2f(T[(size_t)i3 * 64 + lane]) * c3;
    }
    for (; p < s1; ++p) acc += b2f(T[(size_t)csrc[p] * 64 + lane]) * coef[p];
    s[(size_t)node * 64 + lane] = acc + b0[lane] + b1[lane];
}

// ---------------- multi-transpose with output stride ----------------
struct TD { const float* in; unsigned short* out; int K, N, Kp, ldo; };
__global__ void multi_transpose_kernel(TD d0, TD d1, TD d2, TD d3, TD d4, TD d5, TD d6, TD d7) {
    TD d = d0;
    int y = blockIdx.y;
    if (y == 1) d = d1; else if (y == 2) d = d2; else if (y == 3) d = d3;
    else if (y == 4) d = d4; else if (y == 5) d = d5; else if (y == 6) d = d6; else if (y == 7) d = d7;
    int idx = blockIdx.x * 256 + threadIdx.x;
    int total = d.N * d.Kp;
    if (idx >= total) return;
    int n = idx / d.Kp, k = idx - n * d.Kp;
    d.out[(size_t)n * d.ldo + k] = (k < d.K) ? f2bf(d.in[(size_t)k * d.N + n]) : (unsigned short)0;
}

struct G2 {
    const void* A[2]; const unsigned short* Bt[2]; const float* bias[2];
    float* Cf[2]; unsigned short* Cb[2];
};

// ---------------- m97s GEMM: global_load_lds + both-sides chunk-XOR swizzle ----------------
// C[M][N] = A[M][lda](bf16) @ Bt[N][Kp]^T (bf16). 256 threads, 4 waves. K % 32 == 0.
template<int BM, int BN, int WM, int WN>
__global__ __launch_bounds__(256) void m97s_gemm_kernel(
    G2 g, int M, int Kp, int lda, int ldc, int relu) {
    const int z = blockIdx.z;
    const unsigned short* A = (const unsigned short*)(z ? g.A[1] : g.A[0]);
    const unsigned short* Bt = z ? g.Bt[1] : g.Bt[0];
    const float* bias = z ? g.bias[1] : g.bias[0];
    float* Cf = z ? g.Cf[1] : g.Cf[0];
    unsigned short* Cb = z ? g.Cb[1] : g.Cb[0];

    __shared__ __align__(16) unsigned short As[BM * 32];
    __shared__ __align__(16) unsigned short Bs[BN * 32];
    const int t = threadIdx.x, lane = t & 63, wid = t >> 6;
    constexpr int NWC = BN / WN;
    const int wr = wid / NWC, wc = wid % NWC;
    constexpr int MR = WM / 16, NR = WN / 16;
    static_assert((BM / WM) * (BN / WN) == 4, "4 waves");
    constexpr int AI = BM / 64, BI = BN / 64;
    const int row0 = blockIdx.y * BM, col0 = blockIdx.x * BN;
    const int sr = lane >> 2;
    const int sc = ((lane & 3) ^ ((lane >> 3) & 3)) * 8;   // pre-swizzled source chunk
    int arow[AI];
#pragma unroll
    for (int i = 0; i < AI; ++i) {
        int r = row0 + (wid * AI + i) * 16 + sr;
        arow[i] = r < M ? r : M - 1;
    }
    int brow[BI];
#pragma unroll
    for (int i = 0; i < BI; ++i) brow[i] = col0 + (wid * BI + i) * 16 + sr;

    f32x4 acc[MR][NR] = {};
    const int r16 = lane & 15;
    const int kb = (((lane >> 4) ^ ((r16 >> 1) & 3)) * 8);  // swizzled read chunk

    for (int kt = 0; kt < Kp; kt += 32) {
#pragma unroll
        for (int i = 0; i < AI; ++i)
            gload16(A + (size_t)arow[i] * lda + kt + sc, &As[(wid * AI + i) * 512]);
#pragma unroll
        for (int i = 0; i < BI; ++i)
            gload16(Bt + (size_t)brow[i] * Kp + kt + sc, &Bs[(wid * BI + i) * 512]);
        __syncthreads();
        s16x8 af[MR], bfr[NR];
#pragma unroll
        for (int m = 0; m < MR; ++m)
            af[m] = *(const s16x8*)&As[(wr * WM + m * 16 + r16) * 32 + kb];
#pragma unroll
        for (int n = 0; n < NR; ++n)
            bfr[n] = *(const s16x8*)&Bs[(wc * WN + n * 16 + r16) * 32 + kb];
#pragma unroll
        for (int m = 0; m < MR; ++m)
#pragma unroll
            for (int n = 0; n < NR; ++n)
                acc[m][n] = __builtin_amdgcn_mfma_f32_16x16x32_bf16(af[m], bfr[n], acc[m][n], 0, 0, 0);
        __syncthreads();
    }
#pragma unroll
    for (int m = 0; m < MR; ++m) {
#pragma unroll
        for (int n = 0; n < NR; ++n) {
            int col = col0 + wc * WN + n * 16 + r16;
#pragma unroll
            for (int r = 0; r < 4; ++r) {
                int row = row0 + wr * WM + m * 16 + (lane >> 4) * 4 + r;
                if (row < M) {
                    float v = acc[m][n][r] + (bias ? bias[col] : 0.f);
                    if (relu) v = fmaxf(v, 0.f);
                    if (Cf) Cf[(size_t)row * ldc + col] = v;
                    if (Cb) Cb[(size_t)row * ldc + col] = f2bf(v);
                }
            }
        }
    }
}

// ---------------- fused MLP tail: out = relu(relu(fuse@fcW+b)@fc1W+b1)@fc2_w + b2 ----------------
// 64 rows per block, 256 threads. fct [256][256], fc1t [128][256] pre-transposed bf16.
__global__ __launch_bounds__(256) void mlp_tail_kernel(
    const unsigned short* __restrict__ fuse, const unsigned short* __restrict__ fct,
    const float* __restrict__ fc_b, const unsigned short* __restrict__ fc1t,
    const float* __restrict__ fc1_b, const float* __restrict__ fc2_w,
    const float* __restrict__ fc2_b, float* __restrict__ out, int B) {
    __shared__ __align__(16) unsigned short As[64 * 32];     // 4KB staging
    __shared__ __align__(16) unsigned short Bs[256 * 32];    // 16KB staging
    __shared__ __align__(16) unsigned short T1[64 * 264];    // t1 bf16, padded
    __shared__ float part[64];
    const int t = threadIdx.x, lane = t & 63, wid = t >> 6;
    const int row0 = blockIdx.x * 64;
    const int sr = lane >> 2, sc = ((lane & 3) ^ ((lane >> 3) & 3)) * 8;
    const int r16 = lane & 15, q = lane >> 4;
    const int kb = ((q ^ ((r16 >> 1) & 3)) * 8);

    // ---- phase 1: t1 = relu(fuse @ fct^T + fc_b), N=256, each wave owns 64-col slice ----
    {
        f32x4 acc[4][4] = {};
        const int arow = row0 + wid * 16 + sr;
        int brow[4];
#pragma unroll
        for (int i = 0; i < 4; ++i) brow[i] = (wid * 4 + i) * 16 + sr;
        for (int kt = 0; kt < 256; kt += 32) {
            gload16(fuse + (size_t)arow * 256 + kt + sc, &As[wid * 512]);
#pragma unroll
            for (int i = 0; i < 4; ++i)
                gload16(fct + (size_t)brow[i] * 256 + kt + sc, &Bs[(wid * 4 + i) * 512]);
            __syncthreads();
            s16x8 af[4], bfr[4];
#pragma unroll
            for (int m = 0; m < 4; ++m) af[m] = *(const s16x8*)&As[(m * 16 + r16) * 32 + kb];
#pragma unroll
            for (int n = 0; n < 4; ++n) bfr[n] = *(const s16x8*)&Bs[(wid * 64 + n * 16 + r16) * 32 + kb];
#pragma unroll
            for (int m = 0; m < 4; ++m)
#pragma unroll
                for (int n = 0; n < 4; ++n)
                    acc[m][n] = __builtin_amdgcn_mfma_f32_16x16x32_bf16(af[m], bfr[n], acc[m][n], 0, 0, 0);
            __syncthreads();
        }
#pragma unroll
        for (int m = 0; m < 4; ++m)
#pragma unroll
            for (int n = 0; n < 4; ++n) {
                int col = wid * 64 + n * 16 + r16;
#pragma unroll
                for (int r = 0; r < 4; ++r) {
                    int row = m * 16 + q * 4 + r;
                    T1[row * 264 + col] = f2bf(fmaxf(acc[m][n][r] + fc_b[col], 0.f));
                }
            }
    }
    __syncthreads();
    if (t < 64) part[t] = 0.f;

    // ---- phase 2: t2 = t1 @ fc1t^T (+b1, relu in phase 3), N=128, wave owns 32-col slice ----
    f32x4 acc2[4][2] = {};
    {
        int brow[2];
#pragma unroll
        for (int i = 0; i < 2; ++i) brow[i] = (wid * 2 + i) * 16 + sr;
        for (int kt = 0; kt < 256; kt += 32) {
#pragma unroll
            for (int i = 0; i < 2; ++i)
                gload16(fc1t + (size_t)brow[i] * 256 + kt + sc, &Bs[(wid * 2 + i) * 512]);
            __syncthreads();
            s16x8 af[4], bfr[2];
#pragma unroll
            for (int m = 0; m < 4; ++m) af[m] = *(const s16x8*)&T1[(m * 16 + r16) * 264 + kt + q * 8];
#pragma unroll
            for (int n = 0; n < 2; ++n) bfr[n] = *(const s16x8*)&Bs[(wid * 32 + n * 16 + r16) * 32 + kb];
#pragma unroll
            for (int m = 0; m < 4; ++m)
#pragma unroll
                for (int n = 0; n < 2; ++n)
                    acc2[m][n] = __builtin_amdgcn_mfma_f32_16x16x32_bf16(af[m], bfr[n], acc2[m][n], 0, 0, 0);
            __syncthreads();
        }
    }
    // ---- phase 3: per-row dot with fc2_w ----
#pragma unroll
    for (int m = 0; m < 4; ++m)
#pragma unroll
        for (int r = 0; r < 4; ++r) {
            float sv = 0.f;
#pragma unroll
            for (int n = 0; n < 2; ++n) {
                int col = wid * 32 + n * 16 + r16;
                float v = fmaxf(acc2[m][n][r] + fc1_b[col], 0.f);
                sv += v * fc2_w[col];
            }
#pragma unroll
            for (int off = 1; off < 16; off <<= 1) sv += __shfl_xor(sv, off);
            if (r16 == 0) atomicAdd(&part[m * 16 + q * 4 + r], sv);
        }
    __syncthreads();
    if (t < 64 && row0 + t < B) out[row0 + t] = part[t] + fc2_b[0];
}

// ---------------- gene pathway gather -> bf16 feat ----------------
__global__ __launch_bounds__(64) void gene_feat_kernel(
    const float* __restrict__ S, const int* __restrict__ head, const int* __restrict__ tail,
    const int* __restrict__ gene_paths, const void* __restrict__ mask,
    const int* __restrict__ root, unsigned short* __restrict__ feat, const int* __restrict__ flag,
    int B) {
    __shared__ float lds[28 * 64];
    int lane = threadIdx.x;
#pragma unroll
    for (int i = 0; i < 28; ++i) lds[i * 64 + lane] = 0.f;
    int side = blockIdx.y;
    const int* ids = side ? tail : head;
    int gene = ids[blockIdx.x];
    int fl = *flag;
    const unsigned char* mb = (const unsigned char*)mask;
    const int* mi = (const int*)mask;
    const float* mf = (const float*)mask;
    for (int p = 0; p < 32; ++p) {
        int idx = gene * 32 + p;
        int m = (fl == 0) ? mi[idx] : (fl == 1) ? (int)mb[idx] : (mf[idx] != 0.f);
        if (!m) continue;
        int path = gene_paths[idx];
        int r = root[path];
        lds[r * 64 + lane] += S[(size_t)path * 64 + lane];
    }
    unsigned short* frow = feat + ((size_t)side * B + blockIdx.x) * 1792;
#pragma unroll
    for (int i = 0; i < 28; ++i) frow[i * 64 + lane] = f2bf(lds[i * 64 + lane]);
}

// ---------------- batchnorm ----------------
__global__ __launch_bounds__(256) void bn_stats2_kernel(const float* __restrict__ X, int Mrows, int C,
                                                        size_t sideStride, float* __restrict__ part) {
    int blk = blockIdx.x, side = blockIdx.y, c = threadIdx.x;
    const float* Xs = X + (size_t)side * sideStride;
    float s = 0.f, s2 = 0.f;
    if (c < C) {
        for (int r = blk; r < Mrows; r += 32) {
            float v = Xs[(size_t)r * C + c];
            s += v; s2 += v * v;
        }
        float* p = part + ((size_t)(side * 32 + blk) * 2) * C;
        p[c] = s; p[C + c] = s2;
    }
}

__global__ void bn_finalize_kernel(const float* __restrict__ part, int Mrows, int C,
                                   float* __restrict__ mean, float* __restrict__ rstd) {
    int c = blockIdx.x * 256 + threadIdx.x;
    int side = blockIdx.y;
    if (c >= C) return;
    float s = 0.f, s2 = 0.f;
    for (int b = 0; b < 32; ++b) {
        const float* p = part + ((size_t)(side * 32 + b) * 2) * C;
        s += p[c]; s2 += p[C + c];
    }
    float mu = s / Mrows;
    float var = s2 / Mrows - mu * mu;
    mean[side * C + c] = mu;
    rstd[side * C + c] = rsqrtf(var + 1e-5f);
}

__global__ void bn_apply_kernel(const float* __restrict__ X, unsigned short* __restrict__ Y,
                                int Mrows, int C, size_t sideStrideX, size_t sideStrideY,
                                int ldY, int colPerSide,
                                const float* __restrict__ g, const float* __restrict__ b,
                                const float* __restrict__ mean, const float* __restrict__ rstd, int relu) {
    long long idx = (long long)blockIdx.x * 256 + threadIdx.x;
    if (idx >= (long long)Mrows * C) return;
    int side = blockIdx.y;
    int r = (int)(idx / C), c = (int)(idx % C);
    float v = (X[(size_t)side * sideStrideX + idx] - mean[side * C + c]) * rstd[side * C + c] * g[c] + b[c];
    if (relu) v = fmaxf(v, 0.f);
    Y[(size_t)side * sideStrideY + (size_t)r * ldY + side * colPerSide + c] = f2bf(v);
}

// ---------------- launch ----------------
extern "C" void kernel_launch(void* const* d_in, const int* in_sizes, int n_in,
                              void* d_out, int out_size, void* d_ws, size_t ws_size,
                              hipStream_t stream) {
    const float* x[2] = {(const float*)d_in[0], (const float*)d_in[1]};
    const int* esrc = (const int*)d_in[2];
    const int* edst = (const int*)d_in[3];
    const float* ew = (const float*)d_in[4];
    const float* g_w1[2] = {(const float*)d_in[5], (const float*)d_in[9]};
    const float* g_b1[2] = {(const float*)d_in[6], (const float*)d_in[10]};
    const float* g_w2[2] = {(const float*)d_in[7], (const float*)d_in[11]};
    const float* g_b2[2] = {(const float*)d_in[8], (const float*)d_in[12]};
    const float* pl1_w = (const float*)d_in[13];
    const float* pl1_b = (const float*)d_in[14];
    const float* bn1_g = (const float*)d_in[15];
    const float* bn1_b = (const float*)d_in[16];
    const float* pl2_w = (const float*)d_in[17];
    const float* pl2_b = (const float*)d_in[18];
    const float* bn2_g = (const float*)d_in[19];
    const float* bn2_b = (const float*)d_in[20];
    const float* fc_w = (const float*)d_in[21];
    const float* fc_b = (const float*)d_in[22];
    const float* fc1_w = (const float*)d_in[23];
    const float* fc1_b = (const float*)d_in[24];
    const float* fc2_w = (const float*)d_in[25];
    const float* fc2_b = (const float*)d_in[26];
    const int* root = (const int*)d_in[27];
    const int* gene_paths = (const int*)d_in[28];
    const void* gmask = d_in[29];
    const int* head = (const int*)d_in[30];
    const int* tail = (const int*)d_in[31];

    const int P = in_sizes[27];   // 30000
    const int E = in_sizes[2];    // 480000
    const int B = in_sizes[30];   // 4096
    const int IN = 394, Kp1 = 416, H = 256, OUT = 64, GD = 128;
    const int MB = (P + 63) / 64;

    char* ws = (char*)d_ws;
    size_t off = 0;
    auto alloc = [&](size_t bytes) -> char* {
        char* p = ws + off;
        off = (off + bytes + 255) & ~(size_t)255;
        return p;
    };
    int* flag = (int*)alloc(256);
    float* norm = (float*)alloc((size_t)P * 4);
    int* cnt = (int*)alloc((size_t)P * 4);
    int* fillp = (int*)alloc((size_t)P * 4);
    int* rowstart = (int*)alloc((size_t)(P + 1) * 4);
    int* csrc = (int*)alloc((size_t)E * 4);
    float* coef = (float*)alloc((size_t)E * 4);
    unsigned short* W1t = (unsigned short*)alloc((size_t)2 * H * Kp1 * 2);
    unsigned short* W2tc = (unsigned short*)alloc((size_t)OUT * 512 * 2);
    unsigned short* pl1t = (unsigned short*)alloc((size_t)256 * 1792 * 2);
    unsigned short* pl2t = (unsigned short*)alloc((size_t)GD * 256 * 2);
    unsigned short* fct = (unsigned short*)alloc((size_t)256 * 256 * 2);
    unsigned short* fc1t = (unsigned short*)alloc((size_t)GD * 256 * 2);
    float* bn_mean = (float*)alloc((size_t)2 * 256 * 4);
    float* bn_rstd = (float*)alloc((size_t)2 * 256 * 4);
    float* bnpart = (float*)alloc((size_t)2 * 32 * 2 * 256 * 4);
    unsigned short* bufH = (unsigned short*)alloc((size_t)2 * P * H * 2);   // 30.7MB
    unsigned short* bufh1 = (unsigned short*)alloc((size_t)P * 512 * 2);    // 30.7MB
    float* s = (float*)alloc((size_t)P * OUT * 4);                          // 7.7MB
    unsigned short* xbfFull = (unsigned short*)alloc((size_t)2 * P * Kp1 * 2);  // 49.9MB (optional)
    bool batched = (off <= ws_size);
    (void)n_in; (void)out_size;

    // aliases into dead regions:
    unsigned short* bufh2 = bufH;                  // [P][64] summed GEMM2 out (3.84MB)
    unsigned short* feat = bufh1;                  // [2][B][1792] bf16 (29.4MB) after GEMM2
    char* mlp = (char*)bufH + 4194304;             // MLP scratch (past bufh2)
    size_t mo = 0;
    auto malloc2 = [&](size_t bytes) -> char* {
        char* p = mlp + mo;
        mo = (mo + bytes + 255) & ~(size_t)255;
        return p;
    };
    float* z1 = (float*)malloc2((size_t)2 * B * 256 * 4);
    unsigned short* z1b = (unsigned short*)malloc2((size_t)2 * B * 256 * 2);
    float* z2 = (float*)malloc2((size_t)2 * B * GD * 4);
    unsigned short* fuse = (unsigned short*)malloc2((size_t)B * 256 * 2);

    detect_mask_kernel<<<1, 256, 0, stream>>>((const unsigned char*)gmask, 4096, flag);

    // ---- CSR build ----
    long long spanWords = ((char*)(fillp + P) - (char*)norm) / 4;
    zero_f_kernel<<<(int)((spanWords + 255) / 256), 256, 0, stream>>>(norm, spanWords);
    deg_cnt_kernel<<<(E + 255) / 256, 256, 0, stream>>>(edst, ew, norm, cnt, E);
    norm_scan_kernel<<<1 + (P + 1023) / 1024, 1024, 0, stream>>>(cnt, rowstart, norm, P);
    fill_kernel<<<(E + 255) / 256, 256, 0, stream>>>(esrc, edst, ew, norm, rowstart, fillp, csrc, coef, E);

    // ---- weight transposes ----
    {
        TD d0 = {g_w1[0], W1t, IN, H, Kp1, Kp1};
        TD d1 = {g_w1[1], W1t + (size_t)H * Kp1, IN, H, Kp1, Kp1};
        TD d2 = {g_w2[0], W2tc, H, OUT, H, 512};
        TD d3 = {g_w2[1], W2tc + 256, H, OUT, H, 512};
        TD d4 = {pl1_w, pl1t, 1792, 256, 1792, 1792};
        TD d5 = {pl2_w, pl2t, 256, GD, 256, 256};
        TD d6 = {fc_w, fct, 256, 256, 256, 256};
        TD d7 = {fc1_w, fc1t, 256, GD, 256, 256};
        multi_transpose_kernel<<<dim3(1792, 8), 256, 0, stream>>>(d0, d1, d2, d3, d4, d5, d6, d7);
    }

    // ---- GEMM1: x@W1, BN=256 (A panel fetched once) ----
    int xgrid = (P * (Kp1 / 8) + 255) / 256;
    if (batched) {
        xcvt_kernel<<<dim3(xgrid, 2), 256, 0, stream>>>(x[0], x[1], xbfFull, P, IN, Kp1);
        G2 g = {{xbfFull, xbfFull + (size_t)P * Kp1}, {W1t, W1t + (size_t)H * Kp1}, {nullptr, nullptr},
                {nullptr, nullptr}, {bufH, bufH + (size_t)P * H}};
        m97s_gemm_kernel<64, 256, 64, 64><<<dim3(1, MB, 2), 256, 0, stream>>>(
            g, P, Kp1, Kp1, H, 0);
    } else {
        unsigned short* xb = bufh1;
        for (int gi = 0; gi < 2; ++gi) {
            xcvt_kernel<<<dim3(xgrid, 1), 256, 0, stream>>>(x[gi], x[gi], xb, P, IN, Kp1);
            G2 g = {{xb, xb}, {W1t + (size_t)gi * H * Kp1, nullptr}, {nullptr, nullptr},
                    {nullptr, nullptr}, {bufH + (size_t)gi * P * H, nullptr}};
            m97s_gemm_kernel<64, 256, 64, 64><<<dim3(1, MB, 1), 256, 0, stream>>>(
                g, P, Kp1, Kp1, H, 0);
        }
    }

    conv1_agg_kernel<<<dim3((P + 3) / 4, 2), 256, 0, stream>>>(bufH, norm, rowstart, csrc, coef,
                                                               g_b1[0], g_b1[1], bufh1, P);
    // GEMM2 combined: [P][512] @ [512][64] -> summed h2
    {
        G2 g = {{bufh1, nullptr}, {W2tc, nullptr}, {nullptr, nullptr},
                {nullptr, nullptr}, {bufh2, nullptr}};
        m97s_gemm_kernel<64, 64, 32, 32><<<dim3(1, MB, 1), 256, 0, stream>>>(
            g, P, 512, 512, OUT, 0);
    }
    conv2_agg_kernel<<<dim3((P + 3) / 4), 256, 0, stream>>>(bufh2, norm, rowstart, csrc, coef,
                                                            g_b2[0], g_b2[1], s, P);

    // ---- head/tail fuse paths ----
    gene_feat_kernel<<<dim3(B, 2), 64, 0, stream>>>(s, head, tail, gene_paths, gmask, root, feat, flag, B);
    {
        G2 g = {{feat, feat + (size_t)B * 1792}, {pl1t, pl1t}, {pl1_b, pl1_b},
                {z1, z1 + (size_t)B * 256}, {nullptr, nullptr}};
        m97s_gemm_kernel<64, 128, 32, 64><<<dim3(2, B / 64, 2), 256, 0, stream>>>(
            g, B, 1792, 1792, 256, 0);
    }
    bn_stats2_kernel<<<dim3(32, 2), 256, 0, stream>>>(z1, B, 256, (size_t)B * 256, bnpart);
    bn_finalize_kernel<<<dim3(1, 2), 256, 0, stream>>>(bnpart, B, 256, bn_mean, bn_rstd);
    bn_apply_kernel<<<dim3((B * 256 + 255) / 256, 2), 256, 0, stream>>>(
        z1, z1b, B, 256, (size_t)B * 256, (size_t)B * 256, 256, 0,
        bn1_g, bn1_b, bn_mean, bn_rstd, 1);
    {
        G2 g = {{z1b, z1b + (size_t)B * 256}, {pl2t, pl2t}, {pl2_b, pl2_b},
                {z2, z2 + (size_t)B * GD}, {nullptr, nullptr}};
        m97s_gemm_kernel<64, 64, 32, 32><<<dim3(2, B / 64, 2), 256, 0, stream>>>(
            g, B, 256, 256, GD, 0);
    }
    bn_stats2_kernel<<<dim3(32, 2), 256, 0, stream>>>(z2, B, GD, (size_t)B * GD, bnpart);
    bn_finalize_kernel<<<dim3(1, 2), 256, 0, stream>>>(bnpart, B, GD, bn_mean, bn_rstd);
    bn_apply_kernel<<<dim3((B * GD + 255) / 256, 2), 256, 0, stream>>>(
        z2, fuse, B, GD, (size_t)B * GD, 0, 256, GD,
        bn2_g, bn2_b, bn_mean, bn_rstd, 0);

    // ---- fused final MLP ----
    mlp_tail_kernel<<<B / 64, 256, 0, stream>>>(fuse, fct, fc_b, fc1t, fc1_b, fc2_w, fc2_b,
                                                (float*)d_out, B);
}

// Round 7
// 346.133 us; speedup vs baseline: 1.3481x; 1.3481x over previous
//
#include <hip/hip_runtime.h>
#include <cstdint>

typedef __attribute__((ext_vector_type(4))) float f32x4;
typedef __attribute__((ext_vector_type(8))) short s16x8;

__device__ inline unsigned short f2bf(float f) {
    unsigned u = __float_as_uint(f);
    unsigned r = (u + 0x7FFFu + ((u >> 16) & 1u)) >> 16;
    return (unsigned short)r;
}
__device__ inline float b2f(unsigned short h) {
    return __uint_as_float(((unsigned)h) << 16);
}

__device__ inline void gload16(const unsigned short* g, unsigned short* l) {
    __builtin_amdgcn_global_load_lds(
        (const __attribute__((address_space(1))) unsigned int*)g,
        (__attribute__((address_space(3))) unsigned int*)l, 16, 0, 0);
}

// ---------------- prep: detect-mask + zero span + 8 transposes ----------------
struct TD { const float* in; unsigned short* out; int K, N, Kp, ldo; };

__global__ void prep_kernel(const unsigned char* __restrict__ mask, int maskBytes,
                            int* __restrict__ flag, float* __restrict__ zspan, long long zwords,
                            TD d0, TD d1, TD d2, TD d3, TD d4, TD d5, TD d6, TD d7) {
    int y = blockIdx.y;
    if (y == 0) {                       // detect mask storage class
        if (blockIdx.x != 0) return;
        __shared__ int isByte, isFloat;
        if (threadIdx.x == 0) { isByte = 0; isFloat = 0; }
        __syncthreads();
        const unsigned* w = (const unsigned*)mask;
        for (int i = threadIdx.x; i < maskBytes / 4; i += blockDim.x) {
            unsigned v = w[i];
            if (v == 0u || v == 1u) continue;
            if (v == 0x3f800000u) isFloat = 1; else isByte = 1;
        }
        __syncthreads();
        if (threadIdx.x == 0) *flag = isFloat ? 2 : (isByte ? 1 : 0);
        return;
    }
    if (y == 1) {                       // zero norm/cnt/fill/bnparts span
        long long i = (long long)blockIdx.x * 256 + threadIdx.x;
        if (i < zwords) zspan[i] = 0.f;
        return;
    }
    TD d = d0;                          // transposes
    if (y == 3) d = d1; else if (y == 4) d = d2; else if (y == 5) d = d3;
    else if (y == 6) d = d4; else if (y == 7) d = d5; else if (y == 8) d = d6; else if (y == 9) d = d7;
    int idx = blockIdx.x * 256 + threadIdx.x;
    if (idx >= d.N * d.Kp) return;
    int n = idx / d.Kp, k = idx - n * d.Kp;
    d.out[(size_t)n * d.ldo + k] = (k < d.K) ? f2bf(d.in[(size_t)k * d.N + n]) : (unsigned short)0;
}

// ---------------- CSR build ----------------
__global__ void deg_cnt_kernel(const int* __restrict__ dst, const float* __restrict__ ew,
                               float* __restrict__ degw, int* __restrict__ cnt, int E) {
    int e = blockIdx.x * 256 + threadIdx.x;
    if (e >= E) return;
    int d = dst[e];
    unsafeAtomicAdd(&degw[d], ew[e]);
    atomicAdd(&cnt[d], 1);
}

__global__ __launch_bounds__(1024) void norm_scan_kernel(const int* __restrict__ cnt,
                                                         int* __restrict__ rowstart,
                                                         float* __restrict__ degw, int P) {
    int t = threadIdx.x;
    if (blockIdx.x > 0) {
        int i = (blockIdx.x - 1) * 1024 + t;
        if (i < P) degw[i] = rsqrtf(degw[i] + 1.0f);
        return;
    }
    __shared__ int wsum[16];
    __shared__ int carry;
    int lane = t & 63, w = t >> 6;
    if (t == 0) { carry = 0; rowstart[0] = 0; }
    __syncthreads();
    for (int base = 0; base < P; base += 1024) {
        int v = (base + t < P) ? cnt[base + t] : 0;
        int x = v;
#pragma unroll
        for (int off = 1; off < 64; off <<= 1) {
            int y = __shfl_up(x, off);
            if (lane >= off) x += y;
        }
        if (lane == 63) wsum[w] = x;
        __syncthreads();
        if (w == 0) {
            int xs = (lane < 16) ? wsum[lane] : 0;
#pragma unroll
            for (int off = 1; off < 16; off <<= 1) {
                int y = __shfl_up(xs, off);
                if (lane >= off) xs += y;
            }
            if (lane < 16) wsum[lane] = xs;
        }
        __syncthreads();
        int wbase = (w == 0) ? 0 : wsum[w - 1];
        int inc = carry + wbase + x;
        if (base + t < P) rowstart[base + t + 1] = inc;
        __syncthreads();
        if (t == 1023) carry = inc;
        __syncthreads();
    }
}

__global__ void fill_kernel(const int* __restrict__ src, const int* __restrict__ dst,
                            const float* __restrict__ ew, const float* __restrict__ norm,
                            const int* __restrict__ rowstart, int* __restrict__ fill,
                            int* __restrict__ csrc, float* __restrict__ coef, int E) {
    int e = blockIdx.x * 256 + threadIdx.x;
    if (e >= E) return;
    int d = dst[e], sI = src[e];
    int pos = rowstart[d] + atomicAdd(&fill[d], 1);
    csrc[pos] = sI;
    coef[pos] = ew[e] * norm[sI] * norm[d];
}

// ---------------- conv1 aggregation: writes K-concatenated [P][512] ----------------
__global__ __launch_bounds__(256) void conv1_agg_kernel(
    const unsigned short* __restrict__ Hb, const float* __restrict__ norm,
    const int* __restrict__ rowstart, const int* __restrict__ csrc, const float* __restrict__ coef,
    const float* __restrict__ b0, const float* __restrict__ b1,
    unsigned short* __restrict__ out, int P) {
    int node = blockIdx.x * 4 + (threadIdx.x >> 6);
    if (node >= P) return;
    int z = blockIdx.y;
    const unsigned short* H = Hb + (size_t)z * P * 256;
    const float* bias = z ? b1 : b0;
    int lane = threadIdx.x & 63;
    int f4 = lane * 4;
    float nn = norm[node];
    ushort4 hv = *(const ushort4*)(H + (size_t)node * 256 + f4);
    float a0 = b2f(hv.x) * nn * nn, a1 = b2f(hv.y) * nn * nn;
    float a2 = b2f(hv.z) * nn * nn, a3 = b2f(hv.w) * nn * nn;
    int s0 = rowstart[node], s1 = rowstart[node + 1];
    int p = s0;
    for (; p + 4 <= s1; p += 4) {
        int i0 = csrc[p], i1 = csrc[p + 1], i2 = csrc[p + 2], i3 = csrc[p + 3];
        float c0 = coef[p], c1 = coef[p + 1], c2 = coef[p + 2], c3 = coef[p + 3];
        ushort4 v0 = *(const ushort4*)(H + (size_t)i0 * 256 + f4);
        ushort4 v1 = *(const ushort4*)(H + (size_t)i1 * 256 + f4);
        ushort4 v2 = *(const ushort4*)(H + (size_t)i2 * 256 + f4);
        ushort4 v3 = *(const ushort4*)(H + (size_t)i3 * 256 + f4);
        a0 += b2f(v0.x) * c0 + b2f(v1.x) * c1 + b2f(v2.x) * c2 + b2f(v3.x) * c3;
        a1 += b2f(v0.y) * c0 + b2f(v1.y) * c1 + b2f(v2.y) * c2 + b2f(v3.y) * c3;
        a2 += b2f(v0.z) * c0 + b2f(v1.z) * c1 + b2f(v2.z) * c2 + b2f(v3.z) * c3;
        a3 += b2f(v0.w) * c0 + b2f(v1.w) * c1 + b2f(v2.w) * c2 + b2f(v3.w) * c3;
    }
    for (; p < s1; ++p) {
        int i0 = csrc[p];
        float c0 = coef[p];
        ushort4 v0 = *(const ushort4*)(H + (size_t)i0 * 256 + f4);
        a0 += b2f(v0.x) * c0; a1 += b2f(v0.y) * c0; a2 += b2f(v0.z) * c0; a3 += b2f(v0.w) * c0;
    }
    float4 bv = *(const float4*)(bias + f4);
    ushort4 o;
    o.x = f2bf(fmaxf(a0 + bv.x, 0.f));
    o.y = f2bf(fmaxf(a1 + bv.y, 0.f));
    o.z = f2bf(fmaxf(a2 + bv.z, 0.f));
    o.w = f2bf(fmaxf(a3 + bv.w, 0.f));
    *(ushort4*)(out + (size_t)node * 512 + z * 256 + f4) = o;
}

// ---------------- conv2 aggregation on SUMMED table T[P][64] ----------------
__global__ __launch_bounds__(256) void conv2_agg_kernel(
    const unsigned short* __restrict__ T, const float* __restrict__ norm,
    const int* __restrict__ rowstart, const int* __restrict__ csrc, const float* __restrict__ coef,
    const float* __restrict__ b0, const float* __restrict__ b1,
    float* __restrict__ s, int P) {
    int node = blockIdx.x * 4 + (threadIdx.x >> 6);
    if (node >= P) return;
    int lane = threadIdx.x & 63;
    float nn = norm[node];
    float acc = b2f(T[(size_t)node * 64 + lane]) * nn * nn;
    int s0 = rowstart[node], s1 = rowstart[node + 1];
    int p = s0;
    for (; p + 4 <= s1; p += 4) {
        int i0 = csrc[p], i1 = csrc[p + 1], i2 = csrc[p + 2], i3 = csrc[p + 3];
        float c0 = coef[p], c1 = coef[p + 1], c2 = coef[p + 2], c3 = coef[p + 3];
        acc += b2f(T[(size_t)i0 * 64 + lane]) * c0 + b2f(T[(size_t)i1 * 64 + lane]) * c1 +
               b2f(T[(size_t)i2 * 64 + lane]) * c2 + b2f(T[(size_t)i3 * 64 + lane]) * c3;
    }
    for (; p < s1; ++p) acc += b2f(T[(size_t)csrc[p] * 64 + lane]) * coef[p];
    s[(size_t)node * 64 + lane] = acc + b0[lane] + b1[lane];
}

struct G2 {
    const void* A[2]; const unsigned short* Bt[2]; const float* bias[2];
    float* Cf[2]; unsigned short* Cb[2];
};

// ---------------- GEMM1 hybrid: A fp32 reg-staged (padded LDS), B gload+swizzle ----------------
template<int BM, int BN, int WM, int WN>
__global__ __launch_bounds__(256) void gemm1_hybrid_kernel(
    const float* __restrict__ x0, const float* __restrict__ x1,
    const unsigned short* __restrict__ Bt0, const unsigned short* __restrict__ Bt1,
    unsigned short* __restrict__ C0, unsigned short* __restrict__ C1,
    int M, int IN, int Kp, int ldc) {
    const int z = blockIdx.z;
    const float* A = z ? x1 : x0;
    const unsigned short* Bt = z ? Bt1 : Bt0;
    unsigned short* Cb = z ? C1 : C0;

    constexpr int LDK = 40;
    __shared__ __align__(16) unsigned short As[BM * LDK];
    __shared__ __align__(16) unsigned short Bs[BN * 32];
    const int t = threadIdx.x, lane = t & 63, wid = t >> 6;
    constexpr int NWC = BN / WN;
    const int wr = wid / NWC, wc = wid % NWC;
    constexpr int MR = WM / 16, NR = WN / 16;
    static_assert((BM / WM) * (BN / WN) == 4, "4 waves");
    constexpr int BI = BN / 64;
    const int row0 = blockIdx.y * BM, col0 = blockIdx.x * BN;
    const int sr = lane >> 2;
    const int sc = ((lane & 3) ^ ((lane >> 3) & 3)) * 8;
    int brow[BI];
#pragma unroll
    for (int i = 0; i < BI; ++i) brow[i] = col0 + (wid * BI + i) * 16 + sr;
    const int ar = t >> 2, akc = (t & 3) * 8;
    int arowg = row0 + ar; if (arowg >= M) arowg = M - 1;
    const float* aptr = A + (size_t)arowg * IN;

    f32x4 acc[MR][NR] = {};
    const int r16 = lane & 15, q = lane >> 4;
    const int kbA = q * 8;
    const int kbB = ((q ^ ((r16 >> 1) & 3)) * 8);

    for (int kt = 0; kt < Kp; kt += 32) {
#pragma unroll
        for (int i = 0; i < BI; ++i)
            gload16(Bt + (size_t)brow[i] * Kp + kt + sc, &Bs[(wid * BI + i) * 512]);
        {
            int kg = kt + akc;
            float v[8];
            if (kg + 8 <= IN) {
                float2 a = *(const float2*)(aptr + kg);
                float2 b = *(const float2*)(aptr + kg + 2);
                float2 c = *(const float2*)(aptr + kg + 4);
                float2 d = *(const float2*)(aptr + kg + 6);
                v[0]=a.x; v[1]=a.y; v[2]=b.x; v[3]=b.y; v[4]=c.x; v[5]=c.y; v[6]=d.x; v[7]=d.y;
            } else {
#pragma unroll
                for (int j = 0; j < 8; ++j) v[j] = (kg + j < IN) ? aptr[kg + j] : 0.f;
            }
            s16x8 w;
#pragma unroll
            for (int j = 0; j < 8; ++j) w[j] = (short)f2bf(v[j]);
            *(s16x8*)&As[ar * LDK + akc] = w;
        }
        __syncthreads();
        s16x8 af[MR], bfr[NR];
#pragma unroll
        for (int m = 0; m < MR; ++m)
            af[m] = *(const s16x8*)&As[(wr * WM + m * 16 + r16) * LDK + kbA];
#pragma unroll
        for (int n = 0; n < NR; ++n)
            bfr[n] = *(const s16x8*)&Bs[(wc * WN + n * 16 + r16) * 32 + kbB];
#pragma unroll
        for (int m = 0; m < MR; ++m)
#pragma unroll
            for (int n = 0; n < NR; ++n)
                acc[m][n] = __builtin_amdgcn_mfma_f32_16x16x32_bf16(af[m], bfr[n], acc[m][n], 0, 0, 0);
        __syncthreads();
    }
#pragma unroll
    for (int m = 0; m < MR; ++m)
#pragma unroll
        for (int n = 0; n < NR; ++n) {
            int col = col0 + wc * WN + n * 16 + r16;
#pragma unroll
            for (int r = 0; r < 4; ++r) {
                int row = row0 + wr * WM + m * 16 + q * 4 + r;
                if (row < M) Cb[(size_t)row * ldc + col] = f2bf(acc[m][n][r]);
            }
        }
}

// ---------------- m97s GEMM (bf16 A+B gload+swizzle) — used for GEMM2 ----------------
template<int BM, int BN, int WM, int WN>
__global__ __launch_bounds__(256) void m97s_gemm_kernel(
    G2 g, int M, int Kp, int lda, int ldc, int relu) {
    const int z = blockIdx.z;
    const unsigned short* A = (const unsigned short*)(z ? g.A[1] : g.A[0]);
    const unsigned short* Bt = z ? g.Bt[1] : g.Bt[0];
    const float* bias = z ? g.bias[1] : g.bias[0];
    float* Cf = z ? g.Cf[1] : g.Cf[0];
    unsigned short* Cb = z ? g.Cb[1] : g.Cb[0];

    __shared__ __align__(16) unsigned short As[BM * 32];
    __shared__ __align__(16) unsigned short Bs[BN * 32];
    const int t = threadIdx.x, lane = t & 63, wid = t >> 6;
    constexpr int NWC = BN / WN;
    const int wr = wid / NWC, wc = wid % NWC;
    constexpr int MR = WM / 16, NR = WN / 16;
    static_assert((BM / WM) * (BN / WN) == 4, "4 waves");
    constexpr int AI = BM / 64, BI = BN / 64;
    const int row0 = blockIdx.y * BM, col0 = blockIdx.x * BN;
    const int sr = lane >> 2;
    const int sc = ((lane & 3) ^ ((lane >> 3) & 3)) * 8;
    int arow[AI];
#pragma unroll
    for (int i = 0; i < AI; ++i) {
        int r = row0 + (wid * AI + i) * 16 + sr;
        arow[i] = r < M ? r : M - 1;
    }
    int brow[BI];
#pragma unroll
    for (int i = 0; i < BI; ++i) brow[i] = col0 + (wid * BI + i) * 16 + sr;

    f32x4 acc[MR][NR] = {};
    const int r16 = lane & 15;
    const int kb = (((lane >> 4) ^ ((r16 >> 1) & 3)) * 8);

    for (int kt = 0; kt < Kp; kt += 32) {
#pragma unroll
        for (int i = 0; i < AI; ++i)
            gload16(A + (size_t)arow[i] * lda + kt + sc, &As[(wid * AI + i) * 512]);
#pragma unroll
        for (int i = 0; i < BI; ++i)
            gload16(Bt + (size_t)brow[i] * Kp + kt + sc, &Bs[(wid * BI + i) * 512]);
        __syncthreads();
        s16x8 af[MR], bfr[NR];
#pragma unroll
        for (int m = 0; m < MR; ++m)
            af[m] = *(const s16x8*)&As[(wr * WM + m * 16 + r16) * 32 + kb];
#pragma unroll
        for (int n = 0; n < NR; ++n)
            bfr[n] = *(const s16x8*)&Bs[(wc * WN + n * 16 + r16) * 32 + kb];
#pragma unroll
        for (int m = 0; m < MR; ++m)
#pragma unroll
            for (int n = 0; n < NR; ++n)
                acc[m][n] = __builtin_amdgcn_mfma_f32_16x16x32_bf16(af[m], bfr[n], acc[m][n], 0, 0, 0);
        __syncthreads();
    }
#pragma unroll
    for (int m = 0; m < MR; ++m)
#pragma unroll
        for (int n = 0; n < NR; ++n) {
            int col = col0 + wc * WN + n * 16 + r16;
#pragma unroll
            for (int r = 0; r < 4; ++r) {
                int row = row0 + wr * WM + m * 16 + (lane >> 4) * 4 + r;
                if (row < M) {
                    float v = acc[m][n][r] + (bias ? bias[col] : 0.f);
                    if (relu) v = fmaxf(v, 0.f);
                    if (Cf) Cf[(size_t)row * ldc + col] = v;
                    if (Cb) Cb[(size_t)row * ldc + col] = f2bf(v);
                }
            }
        }
}

// ---------------- pl1: m97s + BN-stats epilogue (atomic col sum/sumsq) ----------------
template<int BM, int BN, int WM, int WN>
__global__ __launch_bounds__(256) void pl1_stats_kernel(
    G2 g, int M, int Kp, int lda, int ldc, float* __restrict__ statsPart, int C) {
    const int z = blockIdx.z;
    const unsigned short* A = (const unsigned short*)(z ? g.A[1] : g.A[0]);
    const unsigned short* Bt = z ? g.Bt[1] : g.Bt[0];
    const float* bias = z ? g.bias[1] : g.bias[0];
    float* Cf = z ? g.Cf[1] : g.Cf[0];

    __shared__ __align__(16) unsigned short As[BM * 32];
    __shared__ __align__(16) unsigned short Bs[BN * 32];
    const int t = threadIdx.x, lane = t & 63, wid = t >> 6;
    constexpr int NWC = BN / WN;
    const int wr = wid / NWC, wc = wid % NWC;
    constexpr int MR = WM / 16, NR = WN / 16;
    constexpr int AI = BM / 64, BI = BN / 64;
    const int row0 = blockIdx.y * BM, col0 = blockIdx.x * BN;
    const int sr = lane >> 2;
    const int sc = ((lane & 3) ^ ((lane >> 3) & 3)) * 8;
    int arow[AI];
#pragma unroll
    for (int i = 0; i < AI; ++i) {
        int r = row0 + (wid * AI + i) * 16 + sr;
        arow[i] = r < M ? r : M - 1;
    }
    int brow[BI];
#pragma unroll
    for (int i = 0; i < BI; ++i) brow[i] = col0 + (wid * BI + i) * 16 + sr;

    f32x4 acc[MR][NR] = {};
    const int r16 = lane & 15, q = lane >> 4;
    const int kb = ((q ^ ((r16 >> 1) & 3)) * 8);

    for (int kt = 0; kt < Kp; kt += 32) {
#pragma unroll
        for (int i = 0; i < AI; ++i)
            gload16(A + (size_t)arow[i] * lda + kt + sc, &As[(wid * AI + i) * 512]);
#pragma unroll
        for (int i = 0; i < BI; ++i)
            gload16(Bt + (size_t)brow[i] * Kp + kt + sc, &Bs[(wid * BI + i) * 512]);
        __syncthreads();
        s16x8 af[MR], bfr[NR];
#pragma unroll
        for (int m = 0; m < MR; ++m)
            af[m] = *(const s16x8*)&As[(wr * WM + m * 16 + r16) * 32 + kb];
#pragma unroll
        for (int n = 0; n < NR; ++n)
            bfr[n] = *(const s16x8*)&Bs[(wc * WN + n * 16 + r16) * 32 + kb];
#pragma unroll
        for (int m = 0; m < MR; ++m)
#pragma unroll
            for (int n = 0; n < NR; ++n)
                acc[m][n] = __builtin_amdgcn_mfma_f32_16x16x32_bf16(af[m], bfr[n], acc[m][n], 0, 0, 0);
        __syncthreads();
    }
    float* sp = statsPart + (size_t)z * 2 * C;
#pragma unroll
    for (int n = 0; n < NR; ++n) {
        int col = col0 + wc * WN + n * 16 + r16;
        float sm = 0.f, sq = 0.f;
#pragma unroll
        for (int m = 0; m < MR; ++m)
#pragma unroll
            for (int r = 0; r < 4; ++r) {
                int row = row0 + wr * WM + m * 16 + q * 4 + r;
                float v = acc[m][n][r] + bias[col];
                Cf[(size_t)row * ldc + col] = v;
                sm += v; sq += v * v;
            }
        sm += __shfl_xor(sm, 16); sq += __shfl_xor(sq, 16);
        sm += __shfl_xor(sm, 32); sq += __shfl_xor(sq, 32);
        if (lane < 16) {
            unsafeAtomicAdd(&sp[col], sm);
            unsafeAtomicAdd(&sp[C + col], sq);
        }
    }
}

// ---------------- pl2: A from z1 f32 with inline BN1+relu; epilogue BN2-stats ----------------
template<int BM, int BN, int WM, int WN>
__global__ __launch_bounds__(256) void pl2_bn_stats_kernel(
    const float* __restrict__ z1, const unsigned short* __restrict__ Bt,
    const float* __restrict__ bias, float* __restrict__ z2,
    const float* __restrict__ bn1part, const float* __restrict__ bn1g, const float* __restrict__ bn1b,
    float* __restrict__ bn2part, int Mrows, int Kp, int ldc) {
    const int z = blockIdx.z;
    const float* A = z1 + (size_t)z * Mrows * Kp;
    float* Cf = z2 + (size_t)z * Mrows * ldc;

    constexpr int LDK = 40;
    __shared__ __align__(16) unsigned short As[BM * LDK];
    __shared__ __align__(16) unsigned short Bs[BN * 32];
    __shared__ float sc1[256], sh1[256];
    const int t = threadIdx.x, lane = t & 63, wid = t >> 6;
    {   // inline bn1 finalize (Kp == 256 cols)
        const float* bp = bn1part + (size_t)z * 2 * 256;
        float mu = bp[t] / Mrows;
        float var = bp[256 + t] / Mrows - mu * mu;
        float rstd = rsqrtf(var + 1e-5f);
        float s = rstd * bn1g[t];
        sc1[t] = s; sh1[t] = bn1b[t] - mu * s;
    }
    constexpr int NWC = BN / WN;
    const int wr = wid / NWC, wc = wid % NWC;
    constexpr int MR = WM / 16, NR = WN / 16;
    constexpr int BI = BN / 64;
    const int row0 = blockIdx.y * BM, col0 = blockIdx.x * BN;
    const int sr = lane >> 2;
    const int sc = ((lane & 3) ^ ((lane >> 3) & 3)) * 8;
    int brow[BI];
#pragma unroll
    for (int i = 0; i < BI; ++i) brow[i] = col0 + (wid * BI + i) * 16 + sr;
    const int ar = t >> 2, akc = (t & 3) * 8;
    const float* aptr = A + (size_t)(row0 + ar) * Kp;
    f32x4 acc[MR][NR] = {};
    const int r16 = lane & 15, q = lane >> 4;
    const int kbA = q * 8;
    const int kbB = ((q ^ ((r16 >> 1) & 3)) * 8);
    __syncthreads();

    for (int kt = 0; kt < Kp; kt += 32) {
#pragma unroll
        for (int i = 0; i < BI; ++i)
            gload16(Bt + (size_t)brow[i] * Kp + kt + sc, &Bs[(wid * BI + i) * 512]);
        {
            int kg = kt + akc;
            float4 a = *(const float4*)(aptr + kg);
            float4 b = *(const float4*)(aptr + kg + 4);
            float v[8] = {a.x, a.y, a.z, a.w, b.x, b.y, b.z, b.w};
            s16x8 w;
#pragma unroll
            for (int j = 0; j < 8; ++j)
                w[j] = (short)f2bf(fmaxf(v[j] * sc1[kg + j] + sh1[kg + j], 0.f));
            *(s16x8*)&As[ar * LDK + akc] = w;
        }
        __syncthreads();
        s16x8 af[MR], bfr[NR];
#pragma unroll
        for (int m = 0; m < MR; ++m)
            af[m] = *(const s16x8*)&As[(wr * WM + m * 16 + r16) * LDK + kbA];
#pragma unroll
        for (int n = 0; n < NR; ++n)
            bfr[n] = *(const s16x8*)&Bs[(wc * WN + n * 16 + r16) * 32 + kbB];
#pragma unroll
        for (int m = 0; m < MR; ++m)
#pragma unroll
            for (int n = 0; n < NR; ++n)
                acc[m][n] = __builtin_amdgcn_mfma_f32_16x16x32_bf16(af[m], bfr[n], acc[m][n], 0, 0, 0);
        __syncthreads();
    }
    float* sp = bn2part + (size_t)z * 2 * ldc;
#pragma unroll
    for (int n = 0; n < NR; ++n) {
        int col = col0 + wc * WN + n * 16 + r16;
        float sm = 0.f, sq = 0.f;
#pragma unroll
        for (int m = 0; m < MR; ++m)
#pragma unroll
            for (int r = 0; r < 4; ++r) {
                int row = row0 + wr * WM + m * 16 + q * 4 + r;
                float v = acc[m][n][r] + bias[col];
                Cf[(size_t)row * ldc + col] = v;
                sm += v; sq += v * v;
            }
        sm += __shfl_xor(sm, 16); sq += __shfl_xor(sq, 16);
        sm += __shfl_xor(sm, 32); sq += __shfl_xor(sq, 32);
        if (lane < 16) {
            unsafeAtomicAdd(&sp[col], sm);
            unsafeAtomicAdd(&sp[ldc + col], sq);
        }
    }
}

// ---------------- gene pathway gather -> bf16 feat ----------------
__global__ __launch_bounds__(64) void gene_feat_kernel(
    const float* __restrict__ S, const int* __restrict__ head, const int* __restrict__ tail,
    const int* __restrict__ gene_paths, const void* __restrict__ mask,
    const int* __restrict__ root, unsigned short* __restrict__ feat, const int* __restrict__ flag,
    int B) {
    __shared__ float lds[28 * 64];
    int lane = threadIdx.x;
#pragma unroll
    for (int i = 0; i < 28; ++i) lds[i * 64 + lane] = 0.f;
    int side = blockIdx.y;
    const int* ids = side ? tail : head;
    int gene = ids[blockIdx.x];
    int fl = *flag;
    const unsigned char* mb = (const unsigned char*)mask;
    const int* mi = (const int*)mask;
    const float* mf = (const float*)mask;
    for (int p = 0; p < 32; ++p) {
        int idx = gene * 32 + p;
        int m = (fl == 0) ? mi[idx] : (fl == 1) ? (int)mb[idx] : (mf[idx] != 0.f);
        if (!m) continue;
        int path = gene_paths[idx];
        int r = root[path];
        lds[r * 64 + lane] += S[(size_t)path * 64 + lane];
    }
    unsigned short* frow = feat + ((size_t)side * B + blockIdx.x) * 1792;
#pragma unroll
    for (int i = 0; i < 28; ++i) frow[i * 64 + lane] = f2bf(lds[i * 64 + lane]);
}

// ---------------- fused MLP tail with inline BN2 staging ----------------
__global__ __launch_bounds__(256) void mlp_tail_kernel(
    const float* __restrict__ z2, const float* __restrict__ bn2part,
    const float* __restrict__ bn2g, const float* __restrict__ bn2b,
    const unsigned short* __restrict__ fct, const float* __restrict__ fc_b,
    const unsigned short* __restrict__ fc1t, const float* __restrict__ fc1_b,
    const float* __restrict__ fc2_w, const float* __restrict__ fc2_b,
    float* __restrict__ out, int B) {
    constexpr int LDK = 40;
    __shared__ __align__(16) unsigned short As[64 * LDK];
    __shared__ __align__(16) unsigned short Bs[256 * 32];
    __shared__ __align__(16) unsigned short T1[64 * 264];
    __shared__ float part[64];
    __shared__ float sc2[256], sh2[256];
    const int t = threadIdx.x, lane = t & 63, wid = t >> 6;
    const int row0 = blockIdx.x * 64;
    const int sr = lane >> 2, sc = ((lane & 3) ^ ((lane >> 3) & 3)) * 8;
    const int r16 = lane & 15, q = lane >> 4;
    const int kbA = q * 8;
    const int kbB = ((q ^ ((r16 >> 1) & 3)) * 8);
    const int ar = t >> 2, akc = (t & 3) * 8;

    {   // inline bn2 finalize for 256 fuse columns
        int side = t >> 7, cc = t & 127;
        const float* bp = bn2part + (size_t)side * 256;
        float mu = bp[cc] / B;
        float var = bp[128 + cc] / B - mu * mu;
        float rstd = rsqrtf(var + 1e-5f);
        float s = rstd * bn2g[cc];
        sc2[t] = s; sh2[t] = bn2b[cc] - mu * s;
    }
    __syncthreads();

    // ---- phase 1: T1 = relu(fuse @ fct^T + fc_b); fuse staged from z2 + bn2 ----
    {
        f32x4 acc[4][4] = {};
        int brow[4];
#pragma unroll
        for (int i = 0; i < 4; ++i) brow[i] = (wid * 4 + i) * 16 + sr;
        for (int kt = 0; kt < 256; kt += 32) {
#pragma unroll
            for (int i = 0; i < 4; ++i)
                gload16(fct + (size_t)brow[i] * 256 + kt + sc, &Bs[(wid * 4 + i) * 512]);
            {
                int c0 = kt + akc;
                int side = c0 >> 7, cc = c0 & 127;
                const float* zr = z2 + ((size_t)side * B + row0 + ar) * 128 + cc;
                float4 a = *(const float4*)zr;
                float4 b = *(const float4*)(zr + 4);
                float v[8] = {a.x, a.y, a.z, a.w, b.x, b.y, b.z, b.w};
                s16x8 w;
#pragma unroll
                for (int j = 0; j < 8; ++j) w[j] = (short)f2bf(v[j] * sc2[c0 + j] + sh2[c0 + j]);
                *(s16x8*)&As[ar * LDK + akc] = w;
            }
            __syncthreads();
            s16x8 af[4], bfr[4];
#pragma unroll
            for (int m = 0; m < 4; ++m) af[m] = *(const s16x8*)&As[(m * 16 + r16) * LDK + kbA];
#pragma unroll
            for (int n = 0; n < 4; ++n) bfr[n] = *(const s16x8*)&Bs[(wid * 64 + n * 16 + r16) * 32 + kbB];
#pragma unroll
            for (int m = 0; m < 4; ++m)
#pragma unroll
                for (int n = 0; n < 4; ++n)
                    acc[m][n] = __builtin_amdgcn_mfma_f32_16x16x32_bf16(af[m], bfr[n], acc[m][n], 0, 0, 0);
            __syncthreads();
        }
#pragma unroll
        for (int m = 0; m < 4; ++m)
#pragma unroll
            for (int n = 0; n < 4; ++n) {
                int col = wid * 64 + n * 16 + r16;
#pragma unroll
                for (int r = 0; r < 4; ++r) {
                    int row = m * 16 + q * 4 + r;
                    T1[row * 264 + col] = f2bf(fmaxf(acc[m][n][r] + fc_b[col], 0.f));
                }
            }
    }
    __syncthreads();
    if (t < 64) part[t] = 0.f;

    // ---- phase 2: t2 = t1 @ fc1t^T ----
    f32x4 acc2[4][2] = {};
    {
        int brow[2];
#pragma unroll
        for (int i = 0; i < 2; ++i) brow[i] = (wid * 2 + i) * 16 + sr;
        for (int kt = 0; kt < 256; kt += 32) {
#pragma unroll
            for (int i = 0; i < 2; ++i)
                gload16(fc1t + (size_t)brow[i] * 256 + kt + sc, &Bs[(wid * 2 + i) * 512]);
            __syncthreads();
            s16x8 af[4], bfr[2];
#pragma unroll
            for (int m = 0; m < 4; ++m) af[m] = *(const s16x8*)&T1[(m * 16 + r16) * 264 + kt + q * 8];
#pragma unroll
            for (int n = 0; n < 2; ++n) bfr[n] = *(const s16x8*)&Bs[(wid * 32 + n * 16 + r16) * 32 + kbB];
#pragma unroll
            for (int m = 0; m < 4; ++m)
#pragma unroll
                for (int n = 0; n < 2; ++n)
                    acc2[m][n] = __builtin_amdgcn_mfma_f32_16x16x32_bf16(af[m], bfr[n], acc2[m][n], 0, 0, 0);
            __syncthreads();
        }
    }
    // ---- phase 3: per-row dot with fc2_w ----
#pragma unroll
    for (int m = 0; m < 4; ++m)
#pragma unroll
        for (int r = 0; r < 4; ++r) {
            float sv = 0.f;
#pragma unroll
            for (int n = 0; n < 2; ++n) {
                int col = wid * 32 + n * 16 + r16;
                float v = fmaxf(acc2[m][n][r] + fc1_b[col], 0.f);
                sv += v * fc2_w[col];
            }
#pragma unroll
            for (int off = 1; off < 16; off <<= 1) sv += __shfl_xor(sv, off);
            if (r16 == 0) atomicAdd(&part[m * 16 + q * 4 + r], sv);
        }
    __syncthreads();
    if (t < 64 && row0 + t < B) out[row0 + t] = part[t] + fc2_b[0];
}

// ---------------- launch ----------------
extern "C" void kernel_launch(void* const* d_in, const int* in_sizes, int n_in,
                              void* d_out, int out_size, void* d_ws, size_t ws_size,
                              hipStream_t stream) {
    const float* x[2] = {(const float*)d_in[0], (const float*)d_in[1]};
    const int* esrc = (const int*)d_in[2];
    const int* edst = (const int*)d_in[3];
    const float* ew = (const float*)d_in[4];
    const float* g_w1[2] = {(const float*)d_in[5], (const float*)d_in[9]};
    const float* g_b1[2] = {(const float*)d_in[6], (const float*)d_in[10]};
    const float* g_w2[2] = {(const float*)d_in[7], (const float*)d_in[11]};
    const float* g_b2[2] = {(const float*)d_in[8], (const float*)d_in[12]};
    const float* pl1_w = (const float*)d_in[13];
    const float* pl1_b = (const float*)d_in[14];
    const float* bn1_g = (const float*)d_in[15];
    const float* bn1_b = (const float*)d_in[16];
    const float* pl2_w = (const float*)d_in[17];
    const float* pl2_b = (const float*)d_in[18];
    const float* bn2_g = (const float*)d_in[19];
    const float* bn2_b = (const float*)d_in[20];
    const float* fc_w = (const float*)d_in[21];
    const float* fc_b = (const float*)d_in[22];
    const float* fc1_w = (const float*)d_in[23];
    const float* fc1_b = (const float*)d_in[24];
    const float* fc2_w = (const float*)d_in[25];
    const float* fc2_b = (const float*)d_in[26];
    const int* root = (const int*)d_in[27];
    const int* gene_paths = (const int*)d_in[28];
    const void* gmask = d_in[29];
    const int* head = (const int*)d_in[30];
    const int* tail = (const int*)d_in[31];

    const int P = in_sizes[27];   // 30000
    const int E = in_sizes[2];    // 480000
    const int B = in_sizes[30];   // 4096
    const int IN = 394, Kp1 = 416, H = 256, OUT = 64, GD = 128;
    const int MB = (P + 63) / 64;

    char* ws = (char*)d_ws;
    size_t off = 0;
    auto alloc = [&](size_t bytes) -> char* {
        char* p = ws + off;
        off = (off + bytes + 255) & ~(size_t)255;
        return p;
    };
    int* flag = (int*)alloc(256);
    float* norm = (float*)alloc((size_t)P * 4);        // zero span start
    int* cnt = (int*)alloc((size_t)P * 4);
    int* fillp = (int*)alloc((size_t)P * 4);
    float* bn1part = (float*)alloc((size_t)2 * 2 * 256 * 4);
    float* bn2part = (float*)alloc((size_t)2 * 2 * 128 * 4);
    char* zend = ws + off;                              // zero span end
    int* rowstart = (int*)alloc((size_t)(P + 1) * 4);
    int* csrc = (int*)alloc((size_t)E * 4);
    float* coef = (float*)alloc((size_t)E * 4);
    unsigned short* W1t = (unsigned short*)alloc((size_t)2 * H * Kp1 * 2);
    unsigned short* W2tc = (unsigned short*)alloc((size_t)OUT * 512 * 2);
    unsigned short* pl1t = (unsigned short*)alloc((size_t)256 * 1792 * 2);
    unsigned short* pl2t = (unsigned short*)alloc((size_t)GD * 256 * 2);
    unsigned short* fct = (unsigned short*)alloc((size_t)256 * 256 * 2);
    unsigned short* fc1t = (unsigned short*)alloc((size_t)GD * 256 * 2);
    unsigned short* bufH = (unsigned short*)alloc((size_t)2 * P * H * 2);   // 30.7MB
    unsigned short* bufh1 = (unsigned short*)alloc((size_t)P * 512 * 2);    // 30.7MB
    float* s = (float*)alloc((size_t)P * OUT * 4);                          // 7.7MB
    (void)n_in; (void)out_size; (void)ws_size;

    // aliases into dead regions:
    unsigned short* bufh2 = bufH;                  // [P][64] summed GEMM2 out (3.84MB)
    unsigned short* feat = bufh1;                  // [2][B][1792] bf16 after GEMM2
    char* mlp = (char*)bufH + 4194304;             // past bufh2
    size_t mo = 0;
    auto malloc2 = [&](size_t bytes) -> char* {
        char* p = mlp + mo;
        mo = (mo + bytes + 255) & ~(size_t)255;
        return p;
    };
    float* z1 = (float*)malloc2((size_t)2 * B * 256 * 4);   // [2][B][256]
    float* z2 = (float*)malloc2((size_t)2 * B * GD * 4);    // [2][B][128]

    // ---- 1. prep: detect + zero + 8 transposes ----
    {
        long long zwords = (zend - (char*)norm) / 4;
        TD d0 = {g_w1[0], W1t, IN, H, Kp1, Kp1};
        TD d1 = {g_w1[1], W1t + (size_t)H * Kp1, IN, H, Kp1, Kp1};
        TD d2 = {g_w2[0], W2tc, H, OUT, H, 512};
        TD d3 = {g_w2[1], W2tc + 256, H, OUT, H, 512};
        TD d4 = {pl1_w, pl1t, 1792, 256, 1792, 1792};
        TD d5 = {pl2_w, pl2t, 256, GD, 256, 256};
        TD d6 = {fc_w, fct, 256, 256, 256, 256};
        TD d7 = {fc1_w, fc1t, 256, GD, 256, 256};
        prep_kernel<<<dim3(1792, 10), 256, 0, stream>>>(
            (const unsigned char*)gmask, 4096, flag, norm, zwords,
            d0, d1, d2, d3, d4, d5, d6, d7);
    }

    // ---- 2-4. CSR build ----
    deg_cnt_kernel<<<(E + 255) / 256, 256, 0, stream>>>(edst, ew, norm, cnt, E);
    norm_scan_kernel<<<1 + (P + 1023) / 1024, 1024, 0, stream>>>(cnt, rowstart, norm, P);
    fill_kernel<<<(E + 255) / 256, 256, 0, stream>>>(esrc, edst, ew, norm, rowstart, fillp, csrc, coef, E);

    // ---- 5. GEMM1 hybrid: x fp32 -> bufH bf16 ----
    gemm1_hybrid_kernel<64, 256, 64, 64><<<dim3(1, MB, 2), 256, 0, stream>>>(
        x[0], x[1], W1t, W1t + (size_t)H * Kp1, bufH, bufH + (size_t)P * H, P, IN, Kp1, H);

    // ---- 6. conv1 ----
    conv1_agg_kernel<<<dim3((P + 3) / 4, 2), 256, 0, stream>>>(bufH, norm, rowstart, csrc, coef,
                                                               g_b1[0], g_b1[1], bufh1, P);
    // ---- 7. GEMM2 combined K=512 ----
    {
        G2 g = {{bufh1, nullptr}, {W2tc, nullptr}, {nullptr, nullptr},
                {nullptr, nullptr}, {bufh2, nullptr}};
        m97s_gemm_kernel<64, 64, 32, 32><<<dim3(1, MB, 1), 256, 0, stream>>>(
            g, P, 512, 512, OUT, 0);
    }
    // ---- 8. conv2 ----
    conv2_agg_kernel<<<dim3((P + 3) / 4), 256, 0, stream>>>(bufh2, norm, rowstart, csrc, coef,
                                                            g_b2[0], g_b2[1], s, P);

    // ---- 9. gene gather ----
    gene_feat_kernel<<<dim3(B, 2), 64, 0, stream>>>(s, head, tail, gene_paths, gmask, root, feat, flag, B);

    // ---- 10. pl1 + bn1 stats ----
    {
        G2 g = {{feat, feat + (size_t)B * 1792}, {pl1t, pl1t}, {pl1_b, pl1_b},
                {z1, z1 + (size_t)B * 256}, {nullptr, nullptr}};
        pl1_stats_kernel<64, 128, 32, 64><<<dim3(2, B / 64, 2), 256, 0, stream>>>(
            g, B, 1792, 1792, 256, bn1part, 256);
    }
    // ---- 11. pl2 (inline bn1+relu) + bn2 stats ----
    pl2_bn_stats_kernel<64, 64, 32, 32><<<dim3(2, B / 64, 2), 256, 0, stream>>>(
        z1, pl2t, pl2_b, z2, bn1part, bn1_g, bn1_b, bn2part, B, 256, GD);

    // ---- 12. fused MLP tail (inline bn2) ----
    mlp_tail_kernel<<<B / 64, 256, 0, stream>>>(z2, bn2part, bn2_g, bn2_b, fct, fc_b,
                                                fc1t, fc1_b, fc2_w, fc2_b, (float*)d_out, B);
}